// Round 11
// baseline (246.427 us; speedup 1.0000x reference)
//
#include <hip/hip_runtime.h>
#include <hip/hip_bf16.h>

#define RREL 4
#define DIM 256
#define KDIM 1280      // 4*DIM (means) + DIM (self)
#define KMEAN 1024     // means-only K extent of Y
#define BCAP 32        // bucket capacity per (r,dst) segment

__device__ __forceinline__ float bf2f(unsigned short u) {
    union { unsigned int i; float f; } z; z.i = ((unsigned int)u) << 16; return z.f;
}
__device__ __forceinline__ unsigned short f2bf(float f) {
    __hip_bfloat16 h = __float2bfloat16(f);
    return *(unsigned short*)&h;
}

typedef __attribute__((ext_vector_type(8))) short bf16x8;
typedef __attribute__((ext_vector_type(8))) unsigned short u16x8;
typedef __attribute__((ext_vector_type(4))) float f32x4;
typedef __attribute__((ext_vector_type(4))) float fx4;

// ---------------- fused prep: bucket-scatter + x->bf16 cast + W0 transpose ----------

__global__ __launch_bounds__(256)
void prep(const int* __restrict__ etype, const int* __restrict__ src,
          const int* __restrict__ dst,
          int* __restrict__ counts, int* __restrict__ bucket, int N, int E,
          const float* __restrict__ x, __hip_bfloat16* __restrict__ xb, int n8,
          const float* __restrict__ W0, const float* __restrict__ root0,
          __hip_bfloat16* __restrict__ WT,
          int eb, int cb) {
    int b = blockIdx.x;
    if (b < eb) {                       // count + scatter into buckets
        int e = b * 256 + threadIdx.x;
        if (e < E) {
            int seg = etype[e] * N + dst[e];
            int p = atomicAdd(&counts[seg], 1);
            if (p < BCAP) bucket[(size_t)seg * BCAP + p] = src[e];
        }
    } else if (b < eb + cb) {           // cast x -> bf16, 8 floats/thread (G13)
        int i = (b - eb) * 256 + threadIdx.x;
        if (i < n8) {
            fx4 v0 = *((const fx4*)x + i * 2);
            fx4 v1 = *((const fx4*)x + i * 2 + 1);
            u16x8 u;
            u[0] = f2bf(v0.x); u[1] = f2bf(v0.y); u[2] = f2bf(v0.z); u[3] = f2bf(v0.w);
            u[4] = f2bf(v1.x); u[5] = f2bf(v1.y); u[6] = f2bf(v1.z); u[7] = f2bf(v1.w);
            ((u16x8*)xb)[i] = u;
        }
    } else {                            // WT[n=0..255][k=0..1279] n-major (layer 0)
        __shared__ float tile[32][33];
        int q = b - eb - cb;            // 0..319
        int nblk = q / 40;              // 0..7   (n0 over 256)
        int kblk = q - nblk * 40;       // 0..39  (k0 over 1280)
        int k0 = kblk * 32, n0 = nblk * 32;
        int tx = threadIdx.x & 31, ty = threadIdx.x >> 5;   // 32x8
        const float* srcp;
        int kbase;
        if (k0 < RREL * DIM) { srcp = W0; kbase = k0; } else { srcp = root0; kbase = k0 - RREL * DIM; }
#pragma unroll
        for (int j = 0; j < 4; j++) {
            int k = kbase + ty + j * 8;
            tile[ty + j * 8][tx] = srcp[(size_t)k * DIM + n0 + tx];
        }
        __syncthreads();
#pragma unroll
        for (int j = 0; j < 4; j++) {
            int n = n0 + ty + j * 8;
            WT[(size_t)n * KDIM + k0 + tx] = __float2bfloat16(tile[tx][ty + j * 8]);
        }
    }
}

// ---------------- aggregation (layer 0): Y[i,r*256:+256] = mean_r(xb)  (bf16) ----------------
// Two-quad issue: 8 independent row loads in flight; serial tail only for cnt>8 (~2%).
// Y write nontemporal. Blocks >= ab: edge-weight scatter for collapsed layer 1.

__global__ __launch_bounds__(256)
void aggregate(const __hip_bfloat16* __restrict__ feat, const int* __restrict__ counts,
               const int* __restrict__ bucket, __hip_bfloat16* __restrict__ Y, int N,
               const int* __restrict__ etype, const int* __restrict__ srcv,
               const int* __restrict__ dstv, float* __restrict__ wsr, int E, int ab) {
    if ((int)blockIdx.x >= ab) {        // edge-weight pass
        int e = (blockIdx.x - ab) * 256 + threadIdx.x;
        if (e < E) {
            int r = etype[e];
            int seg = r * N + dstv[e];
            float sc = 1.f / (float)counts[seg];
            atomicAdd(&wsr[(size_t)srcv[e] * RREL + r], sc);
        }
        return;
    }
    int r = threadIdx.x >> 6, lane = threadIdx.x & 63;
    int h = lane >> 5, li = lane & 31;
    int i = blockIdx.x * 2 + h;
    if (i >= N) return;
    int seg = r * N + i;
    int cnt = min(counts[seg], BCAP);
    const unsigned short* fu = (const unsigned short*)feat;
    const int* bk = bucket + (size_t)seg * BCAP;
    float a[8] = {};
    if (cnt > 0) {
        int4 q0 = *(const int4*)bk;            // 16B-aligned
        int4 q1 = *(const int4*)(bk + 4);      // always in-bounds; masked below
        float m1 = (1 < cnt) ? 1.f : 0.f, m2 = (2 < cnt) ? 1.f : 0.f;
        float m3 = (3 < cnt) ? 1.f : 0.f, m4 = (4 < cnt) ? 1.f : 0.f;
        float m5 = (5 < cnt) ? 1.f : 0.f, m6 = (6 < cnt) ? 1.f : 0.f;
        float m7 = (7 < cnt) ? 1.f : 0.f;
        int i0 = q0.x;
        int i1 = m1 ? q0.y : i0;  int i2 = m2 ? q0.z : i0;
        int i3 = m3 ? q0.w : i0;  int i4 = m4 ? q1.x : i0;
        int i5 = m5 ? q1.y : i0;  int i6 = m6 ? q1.z : i0;
        int i7 = m7 ? q1.w : i0;
        u16x8 v0 = *(const u16x8*)(fu + (size_t)i0 * DIM + li * 8);
        u16x8 v1 = *(const u16x8*)(fu + (size_t)i1 * DIM + li * 8);
        u16x8 v2 = *(const u16x8*)(fu + (size_t)i2 * DIM + li * 8);
        u16x8 v3 = *(const u16x8*)(fu + (size_t)i3 * DIM + li * 8);
        u16x8 v4 = *(const u16x8*)(fu + (size_t)i4 * DIM + li * 8);
        u16x8 v5 = *(const u16x8*)(fu + (size_t)i5 * DIM + li * 8);
        u16x8 v6 = *(const u16x8*)(fu + (size_t)i6 * DIM + li * 8);
        u16x8 v7 = *(const u16x8*)(fu + (size_t)i7 * DIM + li * 8);
#pragma unroll
        for (int j = 0; j < 8; j++)
            a[j] = bf2f(v0[j])
                 + m1 * bf2f(v1[j]) + m2 * bf2f(v2[j]) + m3 * bf2f(v3[j])
                 + m4 * bf2f(v4[j]) + m5 * bf2f(v5[j]) + m6 * bf2f(v6[j])
                 + m7 * bf2f(v7[j]);
        for (int k = 8; k < cnt; k += 4) {     // rare tail (cnt>8: ~2%)
            int4 q = *(const int4*)(bk + k);
            float n1 = (k + 1 < cnt) ? 1.f : 0.f;
            float n2 = (k + 2 < cnt) ? 1.f : 0.f;
            float n3 = (k + 3 < cnt) ? 1.f : 0.f;
            int j0 = q.x, j1 = n1 ? q.y : q.x, j2 = n2 ? q.z : q.x, j3 = n3 ? q.w : q.x;
            u16x8 w0 = *(const u16x8*)(fu + (size_t)j0 * DIM + li * 8);
            u16x8 w1 = *(const u16x8*)(fu + (size_t)j1 * DIM + li * 8);
            u16x8 w2 = *(const u16x8*)(fu + (size_t)j2 * DIM + li * 8);
            u16x8 w3 = *(const u16x8*)(fu + (size_t)j3 * DIM + li * 8);
#pragma unroll
            for (int j = 0; j < 8; j++)
                a[j] += bf2f(w0[j]) + n1 * bf2f(w1[j]) + n2 * bf2f(w2[j]) + n3 * bf2f(w3[j]);
        }
    }
    float inv = (cnt > 0) ? 1.f / (float)cnt : 0.f;
    u16x8 u;
#pragma unroll
    for (int j = 0; j < 8; j++) u[j] = f2bf(a[j] * inv);
    __builtin_nontemporal_store(u,
        (u16x8*)((unsigned short*)Y + (size_t)i * KMEAN + r * DIM + li * 8));
}

// ---------------- MFMA GEMM (layer 0) + fused collapsed-layer-1 colsum epilogue ----------
// R11: BM=128 x BN=128 (2x2 waves, 64x64/wave, acc[4][4]) -- doubles arithmetic
// intensity vs R6's BM=64: per K-step MFMA work 16->32 per wave (~160cy) so the
// counted-vmcnt pipeline has 2x compute to hide load latency behind. LDS 64 KB ->
// 2 blocks/CU, 314 blocks all co-resident (no tail). vmcnt(8) = 8 gll/thread/tile.
// Same measured-zero-conflict 8-part XOR swizzle + bijective XCD swizzle.
//   sv[r*256+c] += sum_rows wsr[row][r] * relu_h1[row][c]   (r=0..3)
//   sv[4*256+c] += sum_rows relu_h1[row][c]

#define BMg 128
#define BNg 128
#define BKg 64

__global__ __launch_bounds__(256)
void gemm_mfma(const __hip_bfloat16* __restrict__ A,     // [Mpad, 1024] means
               const __hip_bfloat16* __restrict__ Aself, // [Mpad, 256] feature table
               const __hip_bfloat16* __restrict__ Bt,    // [256, 1280] n-major
               const float* __restrict__ bias,           // [256]
               const float* __restrict__ wsr,            // [N, 4] edge weights
               float* __restrict__ sv,                   // [5*256] output sums
               int Nrows) {
    __shared__ short As[2][BMg * BKg];       // 2 x 16 KB
    __shared__ short Bs[2][BNg * BKg];       // 2 x 16 KB   (64 KB total)
    int t = threadIdx.x;
    int lane = t & 63;
    int w = t >> 6;                           // wave 0..3
    int wr = w >> 1;                          // row half 0..1 (64 rows)
    int wc = w & 1;                           // col half 0..1 (64 cols)

    // bijective XCD-chunked swizzle (m204)
    int nwg = (int)gridDim.x;
    int orig = (int)blockIdx.x;
    int cq = nwg >> 3, cr = nwg & 7;
    int xcd = orig & 7, lin = orig >> 3;
    int wgid = (xcd < cr ? xcd * (cq + 1) : cr * (cq + 1) + (xcd - cr) * cq) + lin;

    int nh = wgid & 1;                        // n-half 0..1
    size_t row0 = (size_t)(wgid >> 1) * BMg;
    int ncol0 = nh * BNg;                     // global col base of this block

    const unsigned short* Ag = (const unsigned short*)A;
    const unsigned short* Sg = (const unsigned short*)Aself;
    const unsigned short* Bg = (const unsigned short*)Bt;

    float bb[4];
#pragma unroll
    for (int ni = 0; ni < 4; ni++)
        bb[ni] = bias[ncol0 + wc * 64 + ni * 16 + (lane & 15)];

    f32x4 acc[4][4] = {};

    // 8 global_load_lds per thread per tile (A:4, B:4) -> steady-state vmcnt(8)
    auto issue_tile = [&](int k0, short* as, short* bs) {
        const unsigned short* Abase;
        int kk, stride;
        if (k0 < KMEAN) { Abase = Ag; kk = k0; stride = KMEAN; }
        else            { Abase = Sg; kk = k0 - KMEAN; stride = DIM; }
#pragma unroll
        for (int h = 0; h < 4; h++) {              // A: 1024 chunks of 16B, 4/thread
            int c = t + h * 256;
            int r = c >> 3, pl = c & 7, pg = pl ^ (r & 7);
            const unsigned short* ga = Abase + (row0 + r) * stride + kk + pg * 8;
            __builtin_amdgcn_global_load_lds(
                (const __attribute__((address_space(1))) void*)ga,
                (__attribute__((address_space(3))) void*)((char*)as + c * 16),
                16, 0, 0);
        }
#pragma unroll
        for (int h = 0; h < 4; h++) {              // B: 1024 chunks of 16B, 4/thread
            int c = t + h * 256;
            int r = c >> 3, pl = c & 7, pg = pl ^ (r & 7);
            const unsigned short* gb = Bg + (size_t)(ncol0 + r) * KDIM + k0 + pg * 8;
            __builtin_amdgcn_global_load_lds(
                (const __attribute__((address_space(1))) void*)gb,
                (__attribute__((address_space(3))) void*)((char*)bs + c * 16),
                16, 0, 0);
        }
    };

    issue_tile(0, As[0], Bs[0]);
    int cur = 0;
    for (int k0 = 0; k0 < KDIM; k0 += BKg) {
        if (k0 + BKg < KDIM) {
            // issue next tile BEFORE waiting on this one: loads stay in flight
            // across the barrier (counted vmcnt, never 0 mid-loop)
            issue_tile(k0 + BKg, As[cur ^ 1], Bs[cur ^ 1]);
            asm volatile("s_waitcnt vmcnt(8)" ::: "memory");
        } else {
            asm volatile("s_waitcnt vmcnt(0)" ::: "memory");
        }
        __builtin_amdgcn_s_barrier();              // all waves' tile-k data visible
        __builtin_amdgcn_sched_barrier(0);         // no ds_read hoisting (rule 18)
        const short* as = As[cur];
        const short* bs = Bs[cur];
#pragma unroll
        for (int ks = 0; ks < 2; ks++) {
            int p = ks * 4 + (lane >> 4);          // 16B part index 0..7
            bf16x8 af[4], bfr[4];
#pragma unroll
            for (int mi = 0; mi < 4; mi++) {
                int m = wr * 64 + mi * 16 + (lane & 15);
                af[mi] = *(const bf16x8*)&as[m * 64 + ((p ^ (m & 7)) * 8)];
            }
#pragma unroll
            for (int ni = 0; ni < 4; ni++) {
                int n = wc * 64 + ni * 16 + (lane & 15);
                bfr[ni] = *(const bf16x8*)&bs[n * 64 + ((p ^ (n & 7)) * 8)];
            }
#pragma unroll
            for (int mi = 0; mi < 4; mi++)
#pragma unroll
                for (int ni = 0; ni < 4; ni++)
                    acc[mi][ni] = __builtin_amdgcn_mfma_f32_16x16x32_bf16(af[mi], bfr[ni], acc[mi][ni], 0, 0, 0);
        }
        __builtin_amdgcn_s_barrier();              // buf[cur] fully read -> reusable
        __builtin_amdgcn_sched_barrier(0);         // no issue-hoisting above barrier
        cur ^= 1;
    }

    // Fused epilogue. C/D layout: col=lane&15, row=(lane>>4)*4+j  [m89-verified].
    // Wave covers rows row0+wr*64..+63 exactly once (mi,j,lane>>4); cols wc*64..+63.
    float a[4][5];
#pragma unroll
    for (int ni = 0; ni < 4; ni++)
#pragma unroll
        for (int s = 0; s < 5; s++) a[ni][s] = 0.f;

#pragma unroll
    for (int mi = 0; mi < 4; mi++) {
#pragma unroll
        for (int j = 0; j < 4; j++) {
            size_t row = row0 + wr * 64 + mi * 16 + (lane >> 4) * 4 + j;
            if (row < (size_t)Nrows) {             // poison rows never touched
                fx4 wv = *(const fx4*)(wsr + row * RREL);
#pragma unroll
                for (int ni = 0; ni < 4; ni++) {
                    float v = fmaxf(acc[mi][ni][j] + bb[ni], 0.f);   // relu BEFORE weighting
                    a[ni][4] += v;
                    a[ni][0] += wv.x * v;
                    a[ni][1] += wv.y * v;
                    a[ni][2] += wv.z * v;
                    a[ni][3] += wv.w * v;
                }
            }
        }
    }
#pragma unroll
    for (int ni = 0; ni < 4; ni++) {
        int col = ncol0 + wc * 64 + ni * 16 + (lane & 15);
#pragma unroll
        for (int s = 0; s < 5; s++) {
            float v = a[ni][s];
            v += __shfl_xor(v, 16, 64);
            v += __shfl_xor(v, 32, 64);
            if ((lane >> 4) == 0) atomicAdd(&sv[s * DIM + col], v);
        }
    }
}

// ---------------- collapsed layer 1 GEMV + fused linear head ----------------

__global__ __launch_bounds__(256)
void gemv_final(const float* __restrict__ sv, const float* __restrict__ W1,
                const float* __restrict__ root1, const float* __restrict__ b1,
                int N, float* __restrict__ g, int* __restrict__ done,
                const float* __restrict__ lw, const float* __restrict__ lb,
                float* __restrict__ out, int nblk) {
    int t = threadIdx.x;
    int kk0 = blockIdx.x * 8;
    float acc = 0.f;
#pragma unroll
    for (int u = 0; u < 8; u++) {
        int kk = kk0 + u;
        int r = kk >> 8;                 // 0..4
        int k = kk & 255;
        const float* row = (r < RREL) ? (W1 + ((size_t)r * DIM + k) * DIM)
                                      : (root1 + (size_t)k * DIM);
        acc += sv[kk] * row[t];
    }
    if (blockIdx.x == 0) acc += (float)N * b1[t];
    atomicAdd(&g[t], acc);
    __threadfence();
    __shared__ int amLast;
    if (t == 0) amLast = (atomicAdd(done, 1) == nblk - 1);
    __syncthreads();
    if (!amLast) return;
    float gv = atomicAdd(&g[t], 0.f);    // device-scope coherent read
    __shared__ float s0[256], s1[256];
    s0[t] = gv * lw[t * 2 + 0];
    s1[t] = gv * lw[t * 2 + 1];
    __syncthreads();
    for (int off = 128; off > 0; off >>= 1) {
        if (t < off) { s0[t] += s0[t + off]; s1[t] += s1[t + off]; }
        __syncthreads();
    }
    if (t == 0) { out[0] = s0[0] + lb[0]; out[1] = s1[0] + lb[1]; }
}

// ---------------- launch ----------------

static inline char* align_up(char* p, size_t a) {
    return (char*)(((uintptr_t)p + (a - 1)) & ~(uintptr_t)(a - 1));
}

extern "C" void kernel_launch(void* const* d_in, const int* in_sizes, int n_in,
                              void* d_out, int out_size, void* d_ws, size_t ws_size,
                              hipStream_t stream) {
    const float* x     = (const float*)d_in[0];
    const int*   eidx  = (const int*)d_in[1];
    const int*   etype = (const int*)d_in[2];
    const float* W0    = (const float*)d_in[4];
    const float* root0 = (const float*)d_in[5];
    const float* b0    = (const float*)d_in[6];
    const float* W1    = (const float*)d_in[7];
    const float* root1 = (const float*)d_in[8];
    const float* b1    = (const float*)d_in[9];
    const float* lin_w = (const float*)d_in[10];
    const float* lin_b = (const float*)d_in[11];
    float* out = (float*)d_out;

    const int N = in_sizes[0] / DIM;
    const int E = in_sizes[2];
    const int RN = RREL * N;
    const int* src = eidx;
    const int* dst = eidx + E;

    const int gx = (N + BMg - 1) / BMg;       // BM=128 tiles
    const int Mpad = gx * BMg;

    char* w = (char*)d_ws;
    int*   counts = (int*)w;   w += (size_t)RN * 4;
    float* wsr    = (float*)w; w += (size_t)N * RREL * 4;
    float* sv     = (float*)w; w += (size_t)5 * DIM * 4;
    float* g      = (float*)w; w += 256 * 4;
    int*   done   = (int*)w;   w += 256;            // padded counter slot
    size_t zero_bytes = (size_t)RN * 4 + (size_t)N * RREL * 4 + 5 * DIM * 4 + 256 * 4 + 256;
    int* bucket = (int*)w; w += (size_t)RN * BCAP * 4;
    w = align_up(w, 16);
    __hip_bfloat16* WT = (__hip_bfloat16*)w; w += (size_t)DIM * KDIM * 2;
    w = align_up(w, 16);
    __hip_bfloat16* Y  = (__hip_bfloat16*)w; w += (size_t)Mpad * KMEAN * 2;
    __hip_bfloat16* xb = (__hip_bfloat16*)w; w += (size_t)Mpad * DIM * 2;

    hipMemsetAsync(counts, 0, zero_bytes, stream);

    int eb = (E + 255) / 256;                 // scatter / edge-weight blocks
    int n8 = N * DIM / 8;
    int cb = (n8 + 255) / 256;                // cast blocks (8 floats/thread)
    int wb = (KDIM / 32) * (DIM / 32);        // W0-transpose blocks (40*8)

    prep<<<eb + cb + wb, 256, 0, stream>>>(etype, src, dst, counts, bucket, N, E,
                                           x, xb, n8, W0, root0, WT, eb, cb);

    int ab = (N + 1) / 2;
    // layer 0 aggregate (+ fused edge-weight pass for collapsed layer 1)
    aggregate<<<ab + eb, 256, 0, stream>>>(xb, counts, bucket, Y, N,
                                           etype, src, dst, wsr, E, ab);
    // layer 0 GEMM with fused layer-1 colsum epilogue -> sv  (314 blocks: m-blk x n-half)
    gemm_mfma<<<gx * 2, 256, 0, stream>>>(Y, xb, WT, b0, wsr, sv, N);
    // collapsed layer 1 GEMV + fused linear head -> out
    int gvb = KDIM / 8;
    gemv_final<<<gvb, 256, 0, stream>>>(sv, W1, root1, b1, N, g, done,
                                        lin_w, lin_b, out, gvb);
}